// Round 3
// baseline (127.645 us; speedup 1.0000x reference)
//
#include <hip/hip_runtime.h>
#include <hip/hip_bf16.h>
#include <cstdint>

#define B_    2
#define C_    256
#define H_    64
#define W_    64
#define P_    (H_*W_)      // 4096
#define N_    4
#define RAD   4
#define K2_   81
#define CTOT  (4*K2_)      // 324

typedef __bf16 bf16x8 __attribute__((ext_vector_type(8)));
typedef float  f32x4  __attribute__((ext_vector_type(4)));

__device__ __forceinline__ void gload_lds16(const void* g, void* l) {
    __builtin_amdgcn_global_load_lds(
        (const __attribute__((address_space(1))) void*)g,
        (__attribute__((address_space(3))) void*)l,
        16, 0, 0);
}

// ---------------------------------------------------------------------------
// Transpose + convert, both maps in one dispatch:
// in (B, C, P) fp32  ->  out (B, P, C) bf16
// ---------------------------------------------------------------------------
__global__ void transpose_cvt(const float* __restrict__ in0,
                              const float* __restrict__ in1,
                              __hip_bfloat16* __restrict__ out0,
                              __hip_bfloat16* __restrict__ out1) {
    __shared__ float tile[32][33];
    const int z     = blockIdx.z;
    const int which = z >> 1;
    const int b     = z & 1;
    const float* in          = which ? in1  : in0;
    __hip_bfloat16* out      = which ? out1 : out0;
    const int p0 = blockIdx.x * 32;
    const int c0 = blockIdx.y * 32;
    const int tx = threadIdx.x;   // 0..31
    const int ty = threadIdx.y;   // 0..7
    const float* src = in + ((size_t)b * C_ + c0) * P_ + p0;
    #pragma unroll
    for (int i = 0; i < 32; i += 8)
        tile[ty + i][tx] = src[(size_t)(ty + i) * P_ + tx];   // tile[c][p]
    __syncthreads();
    __hip_bfloat16* dst = out + ((size_t)b * P_ + p0) * C_ + c0;
    #pragma unroll
    for (int i = 0; i < 32; i += 8)
        dst[(size_t)(ty + i) * C_ + tx] = __float2bfloat16(tile[tx][ty + i]);
}

// ---------------------------------------------------------------------------
// Batched GEMM with fused level-1 pooling AND fused level-0 patch extraction.
// Unchanged from R2 (validated: wide-store epilogue + launch_bounds(256,3)).
// ---------------------------------------------------------------------------
#define TSTR 136   // epilogue tile stride in shorts (272 B -> 16B-aligned)

__global__ __launch_bounds__(256, 3) void gemm_corr(
    const short* __restrict__ f1t,   // (B, 4096, 256) bf16 bits
    const short* __restrict__ f2t,   // (B, 4096, 256) bf16 bits
    const float* __restrict__ coords,
    __hip_bfloat16* __restrict__ corr1,   // (B, 4096, 32, 32) bf16
    __hip_bfloat16* __restrict__ patch0)  // (B, 4096, 4, 120) bf16
{
    __shared__ short smem[128 * TSTR];   // 17408 shorts
    short* As = smem;                    // 128*64
    short* Bs = smem + 8192;             // 128*64

    const int tid  = threadIdx.x;
    const int lane = tid & 63;
    const int wv   = tid >> 6;
    const int wm   = (wv >> 1) * 64;
    const int wn   = (wv & 1) * 64;
    const int b    = blockIdx.z;
    const int bx   = blockIdx.x;
    const int m0   = blockIdx.y * 128;
    const int n0   = bx * 128;
    const int qd   = lane >> 4;
    const int l15  = lane & 15;

    const short* gA[4];
    const short* gB[4];
    int ldsOff[4];
    #pragma unroll
    for (int it = 0; it < 4; ++it) {
        const int ci = it * 256 + tid;
        const int r  = ci >> 3;
        const int cp = ci & 7;
        const int kc = cp ^ (r & 7);
        gA[it] = f1t + ((size_t)(b * P_ + m0 + r)) * C_ + kc * 8;
        gB[it] = f2t + ((size_t)(b * P_ + n0 + r)) * C_ + kc * 8;
        ldsOff[it] = (it * 256 + wv * 64) * 8;
    }

    int aAddr[4][2], bAddr[4][2];
    #pragma unroll
    for (int i = 0; i < 4; ++i) {
        const int m = wm + i * 16 + l15;
        const int n = wn + i * 16 + l15;
        #pragma unroll
        for (int s = 0; s < 2; ++s) {
            const int lc = s * 4 + qd;
            aAddr[i][s] = m * 64 + ((lc ^ (m & 7)) * 8);
            bAddr[i][s] = n * 64 + ((lc ^ (n & 7)) * 8);
        }
    }

    f32x4 zero = {0.f, 0.f, 0.f, 0.f};
    f32x4 acc[4][4];
    #pragma unroll
    for (int mi = 0; mi < 4; ++mi)
        #pragma unroll
        for (int ni = 0; ni < 4; ++ni)
            acc[mi][ni] = zero;

    for (int kt = 0; kt < 4; ++kt) {
        const int k0 = kt * 64;
        #pragma unroll
        for (int it = 0; it < 4; ++it) {
            gload_lds16(gA[it] + k0, As + ldsOff[it]);
            gload_lds16(gB[it] + k0, Bs + ldsOff[it]);
        }
        __syncthreads();
        #pragma unroll
        for (int s = 0; s < 2; ++s) {
            bf16x8 af[4], bfr[4];
            #pragma unroll
            for (int i = 0; i < 4; ++i) {
                af[i]  = *(const bf16x8*)(As + aAddr[i][s]);
                bfr[i] = *(const bf16x8*)(Bs + bAddr[i][s]);
            }
            #pragma unroll
            for (int mi = 0; mi < 4; ++mi)
                #pragma unroll
                for (int ni = 0; ni < 4; ++ni)
                    acc[mi][ni] = __builtin_amdgcn_mfma_f32_16x16x32_bf16(
                        af[mi], bfr[ni], acc[mi][ni], 0, 0, 0);
        }
        __syncthreads();
    }

    const float sc = 0.0625f;   // 1/sqrt(256)
    __hip_bfloat16* tile = (__hip_bfloat16*)smem;
    #pragma unroll
    for (int mi = 0; mi < 4; ++mi) {
        #pragma unroll
        for (int ni = 0; ni < 4; ++ni) {
            #pragma unroll
            for (int r = 0; r < 4; ++r) {
                const int rl = wm + mi * 16 + qd * 4 + r;
                const int cl = wn + ni * 16 + l15;
                tile[rl * TSTR + cl] = __float2bfloat16(acc[mi][ni][r] * sc);
            }
        }
    }
    __syncthreads();

    // ---- fused level-1 pooling (2x2 avg of this block's 2 image rows) ----
    #pragma unroll
    for (int i = 0; i < 16; ++i) {
        const int oid = i * 256 + tid;
        const int pr  = oid >> 5;
        const int pc  = oid & 31;
        const uint32_t u0 = *(const uint32_t*)(smem + pr * TSTR + 2 * pc);
        const uint32_t u1 = *(const uint32_t*)(smem + pr * TSTR + 64 + 2 * pc);
        const float a0 = __uint_as_float(u0 << 16);
        const float a1 = __uint_as_float(u0 & 0xffff0000u);
        const float b0 = __uint_as_float(u1 << 16);
        const float b1 = __uint_as_float(u1 & 0xffff0000u);
        corr1[((size_t)(b * P_ + m0 + pr)) * 1024 + bx * 32 + pc] =
            __float2bfloat16((a0 + a1 + b0 + b1) * 0.25f);
    }

    // ---- fused level-0 patch extraction (wide-store version) ----
    const int row0 = 2 * bx;
    #pragma unroll 1
    for (int pair0 = 0; pair0 < 2; ++pair0) {
        const int pair = pair0 * 256 + tid;   // 0..511
        const int n    = pair & 3;
        const int pi   = pair >> 2;           // 0..127
        const int p    = m0 + pi;
        const float cx = coords[((size_t)((b * N_ + n) * 2 + 0)) * P_ + p];
        const float cy = coords[((size_t)((b * N_ + n) * 2 + 1)) * P_ + p];
        const int x0 = (int)floorf(cx) - RAD;
        const int y0 = (int)floorf(cy) - RAD;
        __hip_bfloat16* pd = patch0 + ((size_t)(b * P_ + p) * N_ + n) * 120;
        #pragma unroll
        for (int rr = 0; rr < 2; ++rr) {
            const int kj = (row0 + rr) - y0;
            if ((unsigned)kj < 10u) {
                const uint16_t* ts = (const uint16_t*)(tile + pi * TSTR + rr * 64);
                uint32_t d[5];
                #pragma unroll
                for (int q = 0; q < 5; ++q) {
                    int g0 = x0 + 2 * q;
                    int g1 = g0 + 1;
                    g0 = min(max(g0, 0), 63);
                    g1 = min(max(g1, 0), 63);
                    d[q] = (uint32_t)ts[g0] | ((uint32_t)ts[g1] << 16);
                }
                uint32_t* dst = (uint32_t*)(pd + kj * 12);   // 8B-aligned
                *(uint2*)(dst)     = make_uint2(d[0], d[1]);
                *(uint2*)(dst + 2) = make_uint2(d[2], d[3]);
                dst[4] = d[4];
            }
        }
    }
}

// ---------------------------------------------------------------------------
// pool23: c1 (bf16, per-p 32x32) -> c2 (f32 16x16) + c3 (f32 8x8).
// One wave per p, wave-private LDS, ZERO barriers (wave LDS ops in-order).
// Arithmetic replicates the old gather Phase-A/pool3 expressions exactly
// (same bf16 source bits, same f32 sum order) -> bit-identical results.
// ---------------------------------------------------------------------------
__global__ __launch_bounds__(256) void pool23(
    const __hip_bfloat16* __restrict__ c1,
    float* __restrict__ c2g,   // (B*P, 256) f32
    float* __restrict__ c3g)   // (B*P, 64)  f32
{
    __shared__ __hip_bfloat16 c1sm[4][1024];
    __shared__ float c2sm[4][256];
    const int tid  = threadIdx.x;
    const int lane = tid & 63;
    const int w    = tid >> 6;
    const int bp   = blockIdx.x * 4 + w;

    // load this p's full 32x32 c1 map (2 KB) coalesced: 2x 16B per lane
    const uint4* s4 = (const uint4*)(c1 + (size_t)bp * 1024);
    uint4* d4 = (uint4*)c1sm[w];
    d4[lane * 2]     = s4[lane * 2];
    d4[lane * 2 + 1] = s4[lane * 2 + 1];

    // c2: 4 outputs per lane (row-major o = lane*4+q), same expression as
    // the old Phase A
    float o4[4];
    #pragma unroll
    for (int q = 0; q < 4; ++q) {
        const int o  = lane * 4 + q;
        const int y2 = o >> 4, x2 = o & 15;
        const uint32_t u0 = *(const uint32_t*)&c1sm[w][(2 * y2) * 32 + 2 * x2];
        const uint32_t u1 = *(const uint32_t*)&c1sm[w][(2 * y2 + 1) * 32 + 2 * x2];
        const float a0 = __uint_as_float(u0 << 16);
        const float a1 = __uint_as_float(u0 & 0xffff0000u);
        const float b0 = __uint_as_float(u1 << 16);
        const float b1 = __uint_as_float(u1 & 0xffff0000u);
        o4[q] = (a0 + a1 + b0 + b1) * 0.25f;
        c2sm[w][o] = o4[q];
    }
    *(float4*)(c2g + (size_t)bp * 256 + lane * 4) =
        make_float4(o4[0], o4[1], o4[2], o4[3]);

    // c3: 1 output per lane, same expression as the old pool3
    const int y3 = lane >> 3, x3 = lane & 7;
    const float* r0 = c2sm[w] + (2 * y3) * 16 + 2 * x3;
    c3g[(size_t)bp * 64 + lane] = (r0[0] + r0[1] + r0[16] + r0[17]) * 0.25f;
}

// ---------------------------------------------------------------------------
// Gather v8: BARRIER-FREE. One block per (b,p), one wave per n; each wave is
// fully independent. Pooling is precomputed (pool23); each wave loads its
// p's c2/c3 (1.25 KB f32, coalesced) into wave-private LDS.
// ---------------------------------------------------------------------------
__global__ __launch_bounds__(256) void gather8(
    const float* __restrict__ coords,
    const __hip_bfloat16* __restrict__ patch0g,
    const __hip_bfloat16* __restrict__ c1,
    const float* __restrict__ c2g,
    const float* __restrict__ c3g,
    float* __restrict__ out) {
    __shared__ float poolw[4][320];    // per wave: [0..255]=c2, [256..319]=c3
    __shared__ float patch[4][440];    // per wave: 4 levels x 110

    const int tid  = threadIdx.x;
    const int lane = tid & 63;
    const int n    = tid >> 6;
    const int bp   = blockIdx.x;       // 0..8191
    const int b    = bp >> 12;
    const int p    = bp & (P_ - 1);

    const __hip_bfloat16* c1b = c1 + (size_t)bp * 1024;

    // ---- geometry, all 4 levels, all lanes ----
    const float cx = coords[((size_t)((b * N_ + n) * 2 + 0)) * P_ + p];
    const float cy = coords[((size_t)((b * N_ + n) * 2 + 1)) * P_ + p];
    int x0i[4], y0i[4];
    float w00[4], w01[4], w10[4], w11[4];
    #pragma unroll
    for (int l = 0; l < 4; ++l) {
        const float inv = (l == 0) ? 1.f : (l == 1) ? 0.5f : (l == 2) ? 0.25f : 0.125f;
        const float x = cx * inv, y = cy * inv;
        const float x0f = floorf(x), y0f = floorf(y);
        const float wx = x - x0f, wy = y - y0f;
        x0i[l] = (int)x0f - RAD;
        y0i[l] = (int)y0f - RAD;
        w00[l] = (1.f - wy) * (1.f - wx);
        w01[l] = (1.f - wy) * wx;
        w10[l] = wy * (1.f - wx);
        w11[l] = wy * wx;
    }

    // ---- prefetch level-0 (stride-12 compact patch) + level-1 (c1) ----
    float pv0[2], pv1[2];
    {
        const __hip_bfloat16* p0 = patch0g + ((size_t)bp * N_ + n) * 120;
        #pragma unroll
        for (int it = 0; it < 2; ++it) {
            const int idx = it * 64 + lane;
            const int r   = idx / 12;
            const int cc  = idx - r * 12;
            const int gr  = y0i[0] + r, gc = x0i[0] + cc;
            float v = 0.f;
            if ((idx < 120) & (cc < 10) & ((unsigned)gr < 64u) &
                ((unsigned)gc < 64u))
                v = __bfloat162float(p0[idx]);
            pv0[it] = v;
        }
    }
    #pragma unroll
    for (int it = 0; it < 2; ++it) {
        const int idx = it * 64 + lane;
        const int r   = idx / 11;
        const int cc  = idx - r * 11;
        const int gr  = y0i[1] + r, gc = x0i[1] + cc;
        float v = 0.f;
        if ((idx < 110) & (cc < 10) & ((unsigned)gr < 32u) &
            ((unsigned)gc < 32u))
            v = __bfloat162float(c1b[(gr << 5) + gc]);
        pv1[it] = v;
    }

    // ---- wave-private pool load: c2 (float4/lane) + c3 (dword/lane) ----
    {
        const float4 v4 = *(const float4*)(c2g + (size_t)bp * 256 + lane * 4);
        *(float4*)&poolw[n][lane * 4] = v4;
        poolw[n][256 + lane] = c3g[(size_t)bp * 64 + lane];
    }
    // no barrier anywhere: poolw[n]/patch[n] are wave-private; wave LDS ops
    // are in program order.

    // ---- patch fill: lvl0 (stride-12 -> 11 remap), lvl1 from regs,
    //      lvl2/3 from poolw ----
    float* pw = patch[n];
    #pragma unroll
    for (int it = 0; it < 2; ++it) {
        const int idx = it * 64 + lane;
        const int r   = idx / 12;
        const int cc  = idx - r * 12;
        if ((idx < 120) & (cc < 11)) pw[r * 11 + cc] = pv0[it];
    }
    #pragma unroll
    for (int it = 0; it < 2; ++it) {
        const int idx = it * 64 + lane;
        if (idx < 110) pw[110 + idx] = pv1[it];
    }
    #pragma unroll
    for (int lvl = 2; lvl < 4; ++lvl) {
        const int hw   = (lvl == 2) ? 16 : 8;
        const int sh   = (lvl == 2) ? 4 : 3;
        const int base = (lvl == 2) ? 0 : 256;
        #pragma unroll
        for (int it = 0; it < 2; ++it) {
            const int idx = it * 64 + lane;
            if (idx < 110) {
                const int r  = idx / 11;
                const int cc = idx - r * 11;
                const int gr = y0i[lvl] + r, gc = x0i[lvl] + cc;
                float v = 0.f;
                if ((cc < 10) & ((unsigned)gr < (unsigned)hw) &
                    ((unsigned)gc < (unsigned)hw))
                    v = poolw[n][base + (gr << sh) + gc];
                pw[lvl * 110 + idx] = v;
            }
        }
    }

    // ---- Phase C: per-level unrolled, 81 outputs each ----
    const size_t obase = ((size_t)(b * N_ + n) * P_ + p) * CTOT;
    #pragma unroll
    for (int lvl = 0; lvl < 4; ++lvl) {
        const float* pl = pw + lvl * 110;
        float* ol = out + obase + lvl * K2_;
        #pragma unroll
        for (int it = 0; it < 2; ++it) {
            const int k2 = it * 64 + lane;
            if (k2 < K2_) {
                const int ki = k2 / 9;        // added to x -> patch col
                const int kj = k2 - ki * 9;   // added to y -> patch row
                const float* pr = pl + kj * 11 + ki;
                ol[k2] = w00[lvl] * pr[0] + w01[lvl] * pr[1] +
                         w10[lvl] * pr[11] + w11[lvl] * pr[12];
            }
        }
    }
}

// ---------------------------------------------------------------------------
extern "C" void kernel_launch(void* const* d_in, const int* in_sizes, int n_in,
                              void* d_out, int out_size, void* d_ws, size_t ws_size,
                              hipStream_t stream) {
    const float* fmap1  = (const float*)d_in[0];
    const float* fmap2  = (const float*)d_in[1];
    const float* coords = (const float*)d_in[2];
    float* out = (float*)d_out;

    char* ws = (char*)d_ws;
    __hip_bfloat16* f1t    = (__hip_bfloat16*)ws;                 //  4,194,304 B
    __hip_bfloat16* f2t    = (__hip_bfloat16*)(ws + 4194304);     //  4,194,304 B
    __hip_bfloat16* c1     = (__hip_bfloat16*)(ws + 8388608);     // 16,777,216 B
    __hip_bfloat16* patch0 = (__hip_bfloat16*)(ws + 25165824);    //  7,864,320 B
    float*          c2     = (float*)(ws + 33030144);             //  8,388,608 B
    float*          c3     = (float*)(ws + 41418752);             //  2,097,152 B

    // 1) transpose+convert both fmaps (one dispatch)
    {
        dim3 grid(P_ / 32, C_ / 32, 2 * B_);
        dim3 blk(32, 8);
        transpose_cvt<<<grid, blk, 0, stream>>>(fmap1, fmap2, f1t, f2t);
    }

    // 2) all-pairs correlation + fused level-1 pooling + fused lvl0 patch
    {
        dim3 grid(P_ / 128, P_ / 128, B_);
        gemm_corr<<<grid, 256, 0, stream>>>((const short*)f1t, (const short*)f2t,
                                            coords, c1, patch0);
    }

    // 3) pool c1 -> c2/c3 (f32, bit-identical to old in-gather pooling)
    pool23<<<B_ * P_ / 4, 256, 0, stream>>>(c1, c2, c3);

    // 4) barrier-free 4-level bilinear gather
    gather8<<<B_ * P_, 256, 0, stream>>>(coords, patch0, c1, c2, c3, out);
}

// Round 4
// 118.681 us; speedup vs baseline: 1.0755x; 1.0755x over previous
//
#include <hip/hip_runtime.h>
#include <hip/hip_bf16.h>
#include <cstdint>

#define B_    2
#define C_    256
#define H_    64
#define W_    64
#define P_    (H_*W_)      // 4096
#define N_    4
#define RAD   4
#define K2_   81
#define CTOT  (4*K2_)      // 324

typedef __bf16 bf16x8 __attribute__((ext_vector_type(8)));
typedef float  f32x4  __attribute__((ext_vector_type(4)));

__device__ __forceinline__ void gload_lds16(const void* g, void* l) {
    __builtin_amdgcn_global_load_lds(
        (const __attribute__((address_space(1))) void*)g,
        (__attribute__((address_space(3))) void*)l,
        16, 0, 0);
}

__device__ __forceinline__ float bf16bits(uint32_t u) {
    return __uint_as_float(u << 16);
}

// ---------------------------------------------------------------------------
// Transpose + convert, both maps in one dispatch:
// in (B, C, P) fp32  ->  out (B, P, C) bf16
// ---------------------------------------------------------------------------
__global__ void transpose_cvt(const float* __restrict__ in0,
                              const float* __restrict__ in1,
                              __hip_bfloat16* __restrict__ out0,
                              __hip_bfloat16* __restrict__ out1) {
    __shared__ float tile[32][33];
    const int z     = blockIdx.z;
    const int which = z >> 1;
    const int b     = z & 1;
    const float* in          = which ? in1  : in0;
    __hip_bfloat16* out      = which ? out1 : out0;
    const int p0 = blockIdx.x * 32;
    const int c0 = blockIdx.y * 32;
    const int tx = threadIdx.x;   // 0..31
    const int ty = threadIdx.y;   // 0..7
    const float* src = in + ((size_t)b * C_ + c0) * P_ + p0;
    #pragma unroll
    for (int i = 0; i < 32; i += 8)
        tile[ty + i][tx] = src[(size_t)(ty + i) * P_ + tx];   // tile[c][p]
    __syncthreads();
    __hip_bfloat16* dst = out + ((size_t)b * P_ + p0) * C_ + c0;
    #pragma unroll
    for (int i = 0; i < 32; i += 8)
        dst[(size_t)(ty + i) * C_ + tx] = __float2bfloat16(tile[tx][ty + i]);
}

// ---------------------------------------------------------------------------
// Batched GEMM with fused level-1 pooling AND fused level-0 patch extraction.
// Unchanged from R2 (validated: wide-store epilogue + launch_bounds(256,3)).
// ---------------------------------------------------------------------------
#define TSTR 136   // epilogue tile stride in shorts (272 B -> 16B-aligned)

__global__ __launch_bounds__(256, 3) void gemm_corr(
    const short* __restrict__ f1t,   // (B, 4096, 256) bf16 bits
    const short* __restrict__ f2t,   // (B, 4096, 256) bf16 bits
    const float* __restrict__ coords,
    __hip_bfloat16* __restrict__ corr1,   // (B, 4096, 32, 32) bf16
    __hip_bfloat16* __restrict__ patch0)  // (B, 4096, 4, 120) bf16
{
    __shared__ short smem[128 * TSTR];   // 17408 shorts
    short* As = smem;                    // 128*64
    short* Bs = smem + 8192;             // 128*64

    const int tid  = threadIdx.x;
    const int lane = tid & 63;
    const int wv   = tid >> 6;
    const int wm   = (wv >> 1) * 64;
    const int wn   = (wv & 1) * 64;
    const int b    = blockIdx.z;
    const int bx   = blockIdx.x;
    const int m0   = blockIdx.y * 128;
    const int n0   = bx * 128;
    const int qd   = lane >> 4;
    const int l15  = lane & 15;

    const short* gA[4];
    const short* gB[4];
    int ldsOff[4];
    #pragma unroll
    for (int it = 0; it < 4; ++it) {
        const int ci = it * 256 + tid;
        const int r  = ci >> 3;
        const int cp = ci & 7;
        const int kc = cp ^ (r & 7);
        gA[it] = f1t + ((size_t)(b * P_ + m0 + r)) * C_ + kc * 8;
        gB[it] = f2t + ((size_t)(b * P_ + n0 + r)) * C_ + kc * 8;
        ldsOff[it] = (it * 256 + wv * 64) * 8;
    }

    int aAddr[4][2], bAddr[4][2];
    #pragma unroll
    for (int i = 0; i < 4; ++i) {
        const int m = wm + i * 16 + l15;
        const int n = wn + i * 16 + l15;
        #pragma unroll
        for (int s = 0; s < 2; ++s) {
            const int lc = s * 4 + qd;
            aAddr[i][s] = m * 64 + ((lc ^ (m & 7)) * 8);
            bAddr[i][s] = n * 64 + ((lc ^ (n & 7)) * 8);
        }
    }

    f32x4 zero = {0.f, 0.f, 0.f, 0.f};
    f32x4 acc[4][4];
    #pragma unroll
    for (int mi = 0; mi < 4; ++mi)
        #pragma unroll
        for (int ni = 0; ni < 4; ++ni)
            acc[mi][ni] = zero;

    for (int kt = 0; kt < 4; ++kt) {
        const int k0 = kt * 64;
        #pragma unroll
        for (int it = 0; it < 4; ++it) {
            gload_lds16(gA[it] + k0, As + ldsOff[it]);
            gload_lds16(gB[it] + k0, Bs + ldsOff[it]);
        }
        __syncthreads();
        #pragma unroll
        for (int s = 0; s < 2; ++s) {
            bf16x8 af[4], bfr[4];
            #pragma unroll
            for (int i = 0; i < 4; ++i) {
                af[i]  = *(const bf16x8*)(As + aAddr[i][s]);
                bfr[i] = *(const bf16x8*)(Bs + bAddr[i][s]);
            }
            #pragma unroll
            for (int mi = 0; mi < 4; ++mi)
                #pragma unroll
                for (int ni = 0; ni < 4; ++ni)
                    acc[mi][ni] = __builtin_amdgcn_mfma_f32_16x16x32_bf16(
                        af[mi], bfr[ni], acc[mi][ni], 0, 0, 0);
        }
        __syncthreads();
    }

    const float sc = 0.0625f;   // 1/sqrt(256)
    __hip_bfloat16* tile = (__hip_bfloat16*)smem;
    #pragma unroll
    for (int mi = 0; mi < 4; ++mi) {
        #pragma unroll
        for (int ni = 0; ni < 4; ++ni) {
            #pragma unroll
            for (int r = 0; r < 4; ++r) {
                const int rl = wm + mi * 16 + qd * 4 + r;
                const int cl = wn + ni * 16 + l15;
                tile[rl * TSTR + cl] = __float2bfloat16(acc[mi][ni][r] * sc);
            }
        }
    }
    __syncthreads();

    // ---- fused level-1 pooling (2x2 avg of this block's 2 image rows) ----
    #pragma unroll
    for (int i = 0; i < 16; ++i) {
        const int oid = i * 256 + tid;
        const int pr  = oid >> 5;
        const int pc  = oid & 31;
        const uint32_t u0 = *(const uint32_t*)(smem + pr * TSTR + 2 * pc);
        const uint32_t u1 = *(const uint32_t*)(smem + pr * TSTR + 64 + 2 * pc);
        const float a0 = __uint_as_float(u0 << 16);
        const float a1 = __uint_as_float(u0 & 0xffff0000u);
        const float b0 = __uint_as_float(u1 << 16);
        const float b1 = __uint_as_float(u1 & 0xffff0000u);
        corr1[((size_t)(b * P_ + m0 + pr)) * 1024 + bx * 32 + pc] =
            __float2bfloat16((a0 + a1 + b0 + b1) * 0.25f);
    }

    // ---- fused level-0 patch extraction (wide-store version) ----
    const int row0 = 2 * bx;
    #pragma unroll 1
    for (int pair0 = 0; pair0 < 2; ++pair0) {
        const int pair = pair0 * 256 + tid;   // 0..511
        const int n    = pair & 3;
        const int pi   = pair >> 2;           // 0..127
        const int p    = m0 + pi;
        const float cx = coords[((size_t)((b * N_ + n) * 2 + 0)) * P_ + p];
        const float cy = coords[((size_t)((b * N_ + n) * 2 + 1)) * P_ + p];
        const int x0 = (int)floorf(cx) - RAD;
        const int y0 = (int)floorf(cy) - RAD;
        __hip_bfloat16* pd = patch0 + ((size_t)(b * P_ + p) * N_ + n) * 120;
        #pragma unroll
        for (int rr = 0; rr < 2; ++rr) {
            const int kj = (row0 + rr) - y0;
            if ((unsigned)kj < 10u) {
                const uint16_t* ts = (const uint16_t*)(tile + pi * TSTR + rr * 64);
                uint32_t d[5];
                #pragma unroll
                for (int q = 0; q < 5; ++q) {
                    int g0 = x0 + 2 * q;
                    int g1 = g0 + 1;
                    g0 = min(max(g0, 0), 63);
                    g1 = min(max(g1, 0), 63);
                    d[q] = (uint32_t)ts[g0] | ((uint32_t)ts[g1] << 16);
                }
                uint32_t* dst = (uint32_t*)(pd + kj * 12);   // 8B-aligned
                *(uint2*)(dst)     = make_uint2(d[0], d[1]);
                *(uint2*)(dst + 2) = make_uint2(d[2], d[3]);
                dst[4] = d[4];
            }
        }
    }
}

// ---------------------------------------------------------------------------
// Gather v9 (R2's gather7 + LDS-staged c1 map):
// - Block DMA-stages its p's full 32x32 c1 map (2 KB) into LDS via
//   global_load_lds (waves 0-1), overlapped with geometry VALU and the
//   coalesced patch0 prefetch.
// - Level-1 patch AND Phase-A pooling both read the LDS copy (bit-identical:
//   same bf16 bits, shift-to-f32). Removes ~110 scattered 2 B global reads
//   per wave that R2 issued into a cold 2 KB map.
// - pool3 (c3) computed redundantly per wave into wave-private LDS: all
//   lanes active, and the 2nd barrier stays the last one (fill is
//   wave-private afterwards). Barrier count unchanged vs R2 (= 2).
// ---------------------------------------------------------------------------
__global__ __launch_bounds__(256) void gather9(
    const float* __restrict__ coords,
    const __hip_bfloat16* __restrict__ patch0g,
    const __hip_bfloat16* __restrict__ c1,
    float* __restrict__ out) {
    __shared__ unsigned short c1sm[1024];   // raw bf16 bits, 32x32 row-major
    __shared__ float c2sm[256];             // 16x16 level-2 pool
    __shared__ float c3w[4][64];            // per-wave 8x8 level-3 pool
    __shared__ float patch[4][440];         // per wave: 4 levels x 110

    const int tid  = threadIdx.x;
    const int lane = tid & 63;
    const int n    = tid >> 6;
    const int bp   = blockIdx.x;       // 0..8191
    const int b    = bp >> 12;
    const int p    = bp & (P_ - 1);

    const __hip_bfloat16* c1b = c1 + (size_t)bp * 1024;

    // ---- DMA-stage c1 map into LDS (waves 0-1; 16 B/lane, 1 KB/wave) ----
    if (n < 2)
        gload_lds16((const short*)c1b + tid * 8, c1sm + (size_t)n * 512);

    // ---- geometry, all 4 levels, all lanes (overlaps the DMA) ----
    const float cx = coords[((size_t)((b * N_ + n) * 2 + 0)) * P_ + p];
    const float cy = coords[((size_t)((b * N_ + n) * 2 + 1)) * P_ + p];
    int x0i[4], y0i[4];
    float w00[4], w01[4], w10[4], w11[4];
    #pragma unroll
    for (int l = 0; l < 4; ++l) {
        const float inv = (l == 0) ? 1.f : (l == 1) ? 0.5f : (l == 2) ? 0.25f : 0.125f;
        const float x = cx * inv, y = cy * inv;
        const float x0f = floorf(x), y0f = floorf(y);
        const float wx = x - x0f, wy = y - y0f;
        x0i[l] = (int)x0f - RAD;
        y0i[l] = (int)y0f - RAD;
        w00[l] = (1.f - wy) * (1.f - wx);
        w01[l] = (1.f - wy) * wx;
        w10[l] = wy * (1.f - wx);
        w11[l] = wy * wx;
    }

    // ---- prefetch level-0 (stride-12 compact patch, coalesced) ----
    float pv0[2];
    {
        const __hip_bfloat16* p0 = patch0g + ((size_t)bp * N_ + n) * 120;
        #pragma unroll
        for (int it = 0; it < 2; ++it) {
            const int idx = it * 64 + lane;
            const int r   = idx / 12;
            const int cc  = idx - r * 12;
            const int gr  = y0i[0] + r, gc = x0i[0] + cc;
            float v = 0.f;
            if ((idx < 120) & (cc < 10) & ((unsigned)gr < 64u) &
                ((unsigned)gc < 64u))
                v = __bfloat162float(p0[idx]);
            pv0[it] = v;
        }
    }

    __syncthreads();   // c1sm ready (barrier drains the global_load_lds)

    // ---- level-1 patch from LDS copy ----
    float pv1[2];
    #pragma unroll
    for (int it = 0; it < 2; ++it) {
        const int idx = it * 64 + lane;
        const int r   = idx / 11;
        const int cc  = idx - r * 11;
        const int gr  = y0i[1] + r, gc = x0i[1] + cc;
        float v = 0.f;
        if ((idx < 110) & (cc < 10) & ((unsigned)gr < 32u) &
            ((unsigned)gc < 32u))
            v = bf16bits(c1sm[(gr << 5) + gc]);
        pv1[it] = v;
    }

    // ---- Phase A: pool c1sm -> c2sm (same unpack/sum order as before) ----
    {
        const int y2 = tid >> 4, x2 = tid & 15;
        const uint32_t u0 = *(const uint32_t*)&c1sm[(2 * y2) * 32 + 2 * x2];
        const uint32_t u1 = *(const uint32_t*)&c1sm[(2 * y2 + 1) * 32 + 2 * x2];
        const float a0 = __uint_as_float(u0 << 16);
        const float a1 = __uint_as_float(u0 & 0xffff0000u);
        const float b0 = __uint_as_float(u1 << 16);
        const float b1 = __uint_as_float(u1 & 0xffff0000u);
        c2sm[tid] = (a0 + a1 + b0 + b1) * 0.25f;
    }
    __syncthreads();   // c2sm ready — last barrier

    // ---- per-wave c3 (redundant, all lanes active, wave-private dest) ----
    {
        const int y3 = lane >> 3, x3 = lane & 7;
        const float* r0 = c2sm + (2 * y3) * 16 + 2 * x3;
        c3w[n][lane] = (r0[0] + r0[1] + r0[16] + r0[17]) * 0.25f;
    }

    // ---- patch fill: lvl0 (stride-12 -> 11 remap), lvl1 from regs,
    //      lvl2 from c2sm (read-only shared), lvl3 from c3w[n] ----
    float* pw = patch[n];
    #pragma unroll
    for (int it = 0; it < 2; ++it) {
        const int idx = it * 64 + lane;
        const int r   = idx / 12;
        const int cc  = idx - r * 12;
        if ((idx < 120) & (cc < 11)) pw[r * 11 + cc] = pv0[it];
    }
    #pragma unroll
    for (int it = 0; it < 2; ++it) {
        const int idx = it * 64 + lane;
        if (idx < 110) pw[110 + idx] = pv1[it];
    }
    #pragma unroll
    for (int lvl = 2; lvl < 4; ++lvl) {
        const int hw = (lvl == 2) ? 16 : 8;
        const int sh = (lvl == 2) ? 4 : 3;
        #pragma unroll
        for (int it = 0; it < 2; ++it) {
            const int idx = it * 64 + lane;
            if (idx < 110) {
                const int r  = idx / 11;
                const int cc = idx - r * 11;
                const int gr = y0i[lvl] + r, gc = x0i[lvl] + cc;
                float v = 0.f;
                if ((cc < 10) & ((unsigned)gr < (unsigned)hw) &
                    ((unsigned)gc < (unsigned)hw))
                    v = (lvl == 2) ? c2sm[(gr << sh) + gc]
                                   : c3w[n][(gr << sh) + gc];
                pw[lvl * 110 + idx] = v;
            }
        }
    }
    // no barrier: patch[n]/c3w[n] are wave-private; wave LDS ops in-order

    // ---- Phase C: per-level unrolled, 81 outputs each ----
    const size_t obase = ((size_t)(b * N_ + n) * P_ + p) * CTOT;
    #pragma unroll
    for (int lvl = 0; lvl < 4; ++lvl) {
        const float* pl = pw + lvl * 110;
        float* ol = out + obase + lvl * K2_;
        #pragma unroll
        for (int it = 0; it < 2; ++it) {
            const int k2 = it * 64 + lane;
            if (k2 < K2_) {
                const int ki = k2 / 9;        // added to x -> patch col
                const int kj = k2 - ki * 9;   // added to y -> patch row
                const float* pr = pl + kj * 11 + ki;
                ol[k2] = w00[lvl] * pr[0] + w01[lvl] * pr[1] +
                         w10[lvl] * pr[11] + w11[lvl] * pr[12];
            }
        }
    }
}

// ---------------------------------------------------------------------------
extern "C" void kernel_launch(void* const* d_in, const int* in_sizes, int n_in,
                              void* d_out, int out_size, void* d_ws, size_t ws_size,
                              hipStream_t stream) {
    const float* fmap1  = (const float*)d_in[0];
    const float* fmap2  = (const float*)d_in[1];
    const float* coords = (const float*)d_in[2];
    float* out = (float*)d_out;

    char* ws = (char*)d_ws;
    __hip_bfloat16* f1t    = (__hip_bfloat16*)ws;                 //  4,194,304 B
    __hip_bfloat16* f2t    = (__hip_bfloat16*)(ws + 4194304);     //  4,194,304 B
    __hip_bfloat16* c1     = (__hip_bfloat16*)(ws + 8388608);     // 16,777,216 B
    __hip_bfloat16* patch0 = (__hip_bfloat16*)(ws + 25165824);    //  7,864,320 B

    // 1) transpose+convert both fmaps (one dispatch)
    {
        dim3 grid(P_ / 32, C_ / 32, 2 * B_);
        dim3 blk(32, 8);
        transpose_cvt<<<grid, blk, 0, stream>>>(fmap1, fmap2, f1t, f2t);
    }

    // 2) all-pairs correlation + fused level-1 pooling + fused lvl0 patch
    {
        dim3 grid(P_ / 128, P_ / 128, B_);
        gemm_corr<<<grid, 256, 0, stream>>>((const short*)f1t, (const short*)f2t,
                                            coords, c1, patch0);
    }

    // 3) LDS-staged 4-level bilinear gather
    gather9<<<B_ * P_, 256, 0, stream>>>(coords, patch0, c1, out);
}